// Round 8
// baseline (129.753 us; speedup 1.0000x reference)
//
#include <hip/hip_runtime.h>

#define LL 8
#define NN 100000
#define HH 128
#define KT 1024
#define BM 32
#define NNHH (NN * HH)

typedef __attribute__((ext_vector_type(4))) float f32x4;
typedef __attribute__((ext_vector_type(8))) short bf16x8;
typedef __attribute__((ext_vector_type(8))) unsigned short u16x8;

__device__ __forceinline__ unsigned short f2bf(float f) {
    unsigned u = __float_as_uint(f);
    unsigned r = ((u >> 16) & 1u) + 0x7fffu;   // RNE
    return (unsigned short)((u + r) >> 16);
}
__device__ __forceinline__ float bf2f(unsigned short s) {
    return __uint_as_float(((unsigned)s) << 16);
}

// Pre-pack w_ref (f32 [128 cols][1024 k]) -> bf16 in fragment order:
// wp[(k8*128 + col)*8 + e] = bf16(w_ref[col][k8*8+e]),  k8 = k/8.
__global__ __launch_bounds__(256) void pack_w_kernel(const float* __restrict__ w_ref,
                                                     unsigned short* __restrict__ wp) {
    int gid = blockIdx.x * 256 + threadIdx.x;   // 0..16383
    int col = gid >> 7;
    int k8  = gid & 127;
    const float* s = w_ref + (size_t)col * KT + (size_t)k8 * 8;
    float4 v0 = *reinterpret_cast<const float4*>(s);
    float4 v1 = *reinterpret_cast<const float4*>(s + 4);
    u16x8 p;
    p[0] = f2bf(v0.x); p[1] = f2bf(v0.y); p[2] = f2bf(v0.z); p[3] = f2bf(v0.w);
    p[4] = f2bf(v1.x); p[5] = f2bf(v1.y); p[6] = f2bf(v1.z); p[7] = f2bf(v1.w);
    *reinterpret_cast<u16x8*>(wp + (size_t)(k8 * 128 + col) * 8) = p;
}

// Block = 32 nodes (3125 blocks exact), 512 threads = 8 waves.
// Wave w covers all 32 nodes x cols [w*16, +16).
// PHASE 1 (barrier-free): stream all 8 layers (depth-4 register pipeline),
//   convert f32->bf16 into the layer-resident LDS tiles, sx in f32 on the fly.
// ONE lgkm-only barrier.
// PHASE 2 (barrier-free): 8x8 MFMAs from resident LDS, B from packed bf16 (L2).
// Then sjk butterfly + one __syncthreads + LDS-fed epilogue. xs read ONCE.
__global__ __launch_bounds__(512, 2)
void gamlp_main(const float* __restrict__ xs,
                const unsigned short* __restrict__ wp,
                const float* __restrict__ b_ref,
                const float* __restrict__ w_att,
                const float* __restrict__ b_att_p,
                const float* __restrict__ alpha_p,
                float* __restrict__ out)
{
    __shared__ unsigned short A_lds[LL][BM * 128];  // 8 x 8KB = 64KB, XOR-swizzled slots
    __shared__ float sjk_lds[BM][8];
    __shared__ float sx_lds[LL][BM];

    const int tid  = threadIdx.x;
    const int lane = tid & 63;
    const int wave = tid >> 6;      // 0..7
    const int colq = lane & 15;
    const int kq   = lane >> 4;
    const int n0   = blockIdx.x * BM;

    const float alpha = *alpha_p;
    const float batt  = *b_att_p;

    // ---- staging map: thread covers (row = tid>>4 in 0..31, 16B slot = tid&15) ----
    const int slot = tid & 15;
    const int row  = tid >> 4;
    const float* src = xs + (size_t)(n0 + row) * HH + slot * 8;
    const int doff = row * 128 + ((slot ^ (row & 15)) * 8);

    // wa_x slice for this thread's k-slot (f32)
    const f32x4 wax0 = *reinterpret_cast<const f32x4*>(w_att + HH + slot * 8);
    const f32x4 wax1 = *reinterpret_cast<const f32x4*>(w_att + HH + slot * 8 + 4);

    // ---- B fragment pointer (packed bf16, L2-resident); wave covers 16 cols ----
    const unsigned short* pB = wp + (size_t)(wave * 16 + colq) * 8;
    const float wr = w_att[wave * 16 + colq];
    const float br = b_ref[wave * 16 + colq];

    f32x4 acc[2];
    acc[0] = (f32x4){0, 0, 0, 0};
    acc[1] = (f32x4){0, 0, 0, 0};

    f32x4 pf[4][2];

#define LOADS(SET, LAY) do {                                                     \
    const size_t g_ = (size_t)(LAY) * NNHH;                                      \
    pf[SET][0] = *reinterpret_cast<const f32x4*>(src + g_);                      \
    pf[SET][1] = *reinterpret_cast<const f32x4*>(src + g_ + 4);                  \
} while (0)

#define CONVERT_WRITE(SET, LAY) do {                                             \
    float pa_ = pf[SET][0][0]*wax0[0] + pf[SET][0][1]*wax0[1]                    \
              + pf[SET][0][2]*wax0[2] + pf[SET][0][3]*wax0[3]                    \
              + pf[SET][1][0]*wax1[0] + pf[SET][1][1]*wax1[1]                    \
              + pf[SET][1][2]*wax1[2] + pf[SET][1][3]*wax1[3];                   \
    pa_ += __shfl_xor(pa_, 1); pa_ += __shfl_xor(pa_, 2);                        \
    pa_ += __shfl_xor(pa_, 4); pa_ += __shfl_xor(pa_, 8);                        \
    if (slot == 0) sx_lds[LAY][row] = pa_;                                       \
    u16x8 pk_;                                                                   \
    _Pragma("unroll")                                                            \
    for (int e_ = 0; e_ < 4; e_++) {                                             \
        pk_[e_]   = f2bf(pf[SET][0][e_]);                                        \
        pk_[e_+4] = f2bf(pf[SET][1][e_]);                                        \
    }                                                                            \
    *reinterpret_cast<u16x8*>(&A_lds[LAY][doff]) = pk_;                          \
} while (0)

    // ---- PHASE 1: stream + convert all 8 layers, no barriers ----
    LOADS(0, 0);
    LOADS(1, 1);
    LOADS(2, 2);
    LOADS(3, 3);
    #pragma unroll
    for (int l = 0; l < 8; l++) {
        CONVERT_WRITE(l & 3, l);
        if (l + 4 < 8) LOADS(l & 3, l + 4);
    }

    // one barrier: all LDS tiles + sx visible; no vmcnt drain needed
    asm volatile("s_waitcnt lgkmcnt(0)" ::: "memory");
    __builtin_amdgcn_s_barrier();

    // ---- PHASE 2: 64 MFMAs from resident LDS, no barriers ----
    #pragma unroll
    for (int s = 0; s < 8; s++) {
        const int k8base = s * 16;
        bf16x8 bc = *reinterpret_cast<const bf16x8*>(pB + (size_t)(k8base + kq) * 1024);
        #pragma unroll
        for (int c = 0; c < 4; c++) {
            bf16x8 bn;
            if (c < 3)
                bn = *reinterpret_cast<const bf16x8*>(pB + (size_t)(k8base + (c + 1) * 4 + kq) * 1024);
            bf16x8 af[2];
            #pragma unroll
            for (int m = 0; m < 2; m++) {
                int r = m * 16 + colq;
                af[m] = *reinterpret_cast<const bf16x8*>(
                    &A_lds[s][r * 128 + (((c * 4 + kq) ^ colq) * 8)]);
            }
            acc[0] = __builtin_amdgcn_mfma_f32_16x16x32_bf16(af[0], bc, acc[0], 0, 0, 0);
            acc[1] = __builtin_amdgcn_mfma_f32_16x16x32_bf16(af[1], bc, acc[1], 0, 0, 0);
            bc = bn;
        }
    }

    // ---- sjk: sum over this wave's 16 cols of prelu(jk + b_ref) * wa_ref ----
    // D layout: col = wave*16 + colq, node = m*16 + kq*4 + r
    #pragma unroll
    for (int m = 0; m < 2; m++) {
        float sr[4];
        #pragma unroll
        for (int r = 0; r < 4; r++) {
            float v = acc[m][r] + br;
            v = (v >= 0.f) ? v : alpha * v;
            float sv = v * wr;
            sv += __shfl_xor(sv, 1);
            sv += __shfl_xor(sv, 2);
            sv += __shfl_xor(sv, 4);
            sv += __shfl_xor(sv, 8);
            sr[r] = sv;
        }
        if (colq == 0) {
            #pragma unroll
            for (int r = 0; r < 4; r++)
                sjk_lds[m * 16 + kq * 4 + r][wave] = sr[r];
        }
    }
    __syncthreads();

    // ---- epilogue: softmax from LDS scores + weighted sum from LDS bf16 tiles ----
    // Thread handles (node = row, slot); xs NOT re-read.
    {
        const int node = row;
        const int boff = node * 128 + ((slot ^ (node & 15)) * 8);
        float sjk = 0.f;
        #pragma unroll
        for (int w8 = 0; w8 < 8; w8++) sjk += sjk_lds[node][w8];
        float sc[LL], mx = 0.f;
        #pragma unroll
        for (int l = 0; l < LL; l++) {
            float sv = sjk + sx_lds[l][node] + batt;
            sv = fmaxf(sv, 0.f);
            sc[l] = sv;
            mx = fmaxf(mx, sv);
        }
        float den = 0.f;
        #pragma unroll
        for (int l = 0; l < LL; l++) { sc[l] = __expf(sc[l] - mx); den += sc[l]; }
        float inv = 1.f / den;
        f32x4 o0 = (f32x4){0.f, 0.f, 0.f, 0.f};
        f32x4 o1 = (f32x4){0.f, 0.f, 0.f, 0.f};
        #pragma unroll
        for (int l = 0; l < LL; l++) {
            u16x8 v = *reinterpret_cast<const u16x8*>(&A_lds[l][boff]);
            float wl = sc[l] * inv;
            #pragma unroll
            for (int e = 0; e < 4; e++) {
                o0[e] += wl * bf2f(v[e]);
                o1[e] += wl * bf2f(v[e + 4]);
            }
        }
        float* op = out + (size_t)(n0 + node) * HH + slot * 8;
        *reinterpret_cast<f32x4*>(op)     = o0;
        *reinterpret_cast<f32x4*>(op + 4) = o1;
    }
#undef LOADS
#undef CONVERT_WRITE
}

extern "C" void kernel_launch(void* const* d_in, const int* in_sizes, int n_in,
                              void* d_out, int out_size, void* d_ws, size_t ws_size,
                              hipStream_t stream) {
    const float* xs     = (const float*)d_in[0];
    const float* w_ref  = (const float*)d_in[1];
    const float* b_ref  = (const float*)d_in[2];
    const float* w_att  = (const float*)d_in[3];
    const float* b_att  = (const float*)d_in[4];
    const float* alpha  = (const float*)d_in[5];
    float* out = (float*)d_out;
    unsigned short* wp = (unsigned short*)d_ws;   // 256 KB packed bf16 weights

    pack_w_kernel<<<64, 256, 0, stream>>>(w_ref, wp);
    const int grid = NN / BM;                     // 3125, exact
    gamlp_main<<<grid, 512, 0, stream>>>(xs, wp, b_ref, w_att, b_att, alpha, out);
}

// Round 9
// 121.373 us; speedup vs baseline: 1.0690x; 1.0690x over previous
//
#include <hip/hip_runtime.h>

#define LL 8
#define NN 100000
#define HH 128
#define KT 1024
#define BM 32
#define NNHH (NN * HH)

typedef __attribute__((ext_vector_type(4))) float f32x4;
typedef __attribute__((ext_vector_type(8))) short bf16x8;
typedef __attribute__((ext_vector_type(8))) unsigned short u16x8;

__device__ __forceinline__ unsigned short f2bf(float f) {
    unsigned u = __float_as_uint(f);
    unsigned r = ((u >> 16) & 1u) + 0x7fffu;   // RNE
    return (unsigned short)((u + r) >> 16);
}
__device__ __forceinline__ float bf2f(unsigned short s) {
    return __uint_as_float(((unsigned)s) << 16);
}
__device__ __forceinline__ f32x4 ntload4(const float* p) {
    return __builtin_nontemporal_load(reinterpret_cast<const f32x4*>(p));
}

// Pre-pack w_ref (f32 [128 cols][1024 k]) -> bf16 in fragment order:
// wp[(k8*128 + col)*8 + e] = bf16(w_ref[col][k8*8+e]),  k8 = k/8.
__global__ __launch_bounds__(256) void pack_w_kernel(const float* __restrict__ w_ref,
                                                     unsigned short* __restrict__ wp) {
    int gid = blockIdx.x * 256 + threadIdx.x;   // 0..16383
    int col = gid >> 7;
    int k8  = gid & 127;
    const float* s = w_ref + (size_t)col * KT + (size_t)k8 * 8;
    float4 v0 = *reinterpret_cast<const float4*>(s);
    float4 v1 = *reinterpret_cast<const float4*>(s + 4);
    u16x8 p;
    p[0] = f2bf(v0.x); p[1] = f2bf(v0.y); p[2] = f2bf(v0.z); p[3] = f2bf(v0.w);
    p[4] = f2bf(v1.x); p[5] = f2bf(v1.y); p[6] = f2bf(v1.z); p[7] = f2bf(v1.w);
    *reinterpret_cast<u16x8*>(wp + (size_t)(k8 * 128 + col) * 8) = p;
}

// Block = 32 nodes (3125 blocks exact), 512 threads = 8 waves; wave w: 32 nodes
// x cols [w*16,+16). r7's INTERLEAVED per-layer pipeline (stream||convert||MFMA,
// lgkm-only barrier per step, loads stay in flight across barriers), now with:
//  - 16 waves/CU TLP (512 thr, 2 blocks/CU),
//  - B register double-buffer across steps (no in-step L2 latency chain),
//  - nontemporal xs loads / out stores (protect wp L2 residency).
// All 8 layers' bf16 tiles stay LDS-resident; epilogue feeds from LDS; xs read ONCE.
__global__ __launch_bounds__(512, 2)
void gamlp_main(const float* __restrict__ xs,
                const unsigned short* __restrict__ wp,
                const float* __restrict__ b_ref,
                const float* __restrict__ w_att,
                const float* __restrict__ b_att_p,
                const float* __restrict__ alpha_p,
                float* __restrict__ out)
{
    __shared__ unsigned short A_lds[LL][BM * 128];  // 8 x 8KB = 64KB, XOR-swizzled slots
    __shared__ float sjk_lds[BM][8];
    __shared__ float sx_lds[LL][BM];

    const int tid  = threadIdx.x;
    const int lane = tid & 63;
    const int wave = tid >> 6;      // 0..7
    const int colq = lane & 15;
    const int kq   = lane >> 4;
    const int n0   = blockIdx.x * BM;

    const float alpha = *alpha_p;
    const float batt  = *b_att_p;

    // ---- staging map: thread covers (row = tid>>4 in 0..31, 16B slot = tid&15) ----
    const int slot = tid & 15;
    const int row  = tid >> 4;
    const float* src = xs + (size_t)(n0 + row) * HH + slot * 8;
    const int doff = row * 128 + ((slot ^ (row & 15)) * 8);

    // wa_x slice for this thread's k-slot (f32)
    const f32x4 wax0 = *reinterpret_cast<const f32x4*>(w_att + HH + slot * 8);
    const f32x4 wax1 = *reinterpret_cast<const f32x4*>(w_att + HH + slot * 8 + 4);

    // ---- B fragment pointer (packed bf16, L2-resident); wave covers 16 cols ----
    const unsigned short* pB = wp + (size_t)(wave * 16 + colq) * 8;
    const float wr = w_att[wave * 16 + colq];
    const float br = b_ref[wave * 16 + colq];

    f32x4 acc[2];
    acc[0] = (f32x4){0, 0, 0, 0};
    acc[1] = (f32x4){0, 0, 0, 0};

    f32x4 pf[3][2];

#define LOADS(SET, LAY) do {                                                     \
    const size_t g_ = (size_t)(LAY) * NNHH;                                      \
    pf[SET][0] = ntload4(src + g_);                                              \
    pf[SET][1] = ntload4(src + g_ + 4);                                          \
} while (0)

#define CONVERT_WRITE(SET, LAY) do {                                             \
    float pa_ = pf[SET][0][0]*wax0[0] + pf[SET][0][1]*wax0[1]                    \
              + pf[SET][0][2]*wax0[2] + pf[SET][0][3]*wax0[3]                    \
              + pf[SET][1][0]*wax1[0] + pf[SET][1][1]*wax1[1]                    \
              + pf[SET][1][2]*wax1[2] + pf[SET][1][3]*wax1[3];                   \
    pa_ += __shfl_xor(pa_, 1); pa_ += __shfl_xor(pa_, 2);                        \
    pa_ += __shfl_xor(pa_, 4); pa_ += __shfl_xor(pa_, 8);                        \
    if (slot == 0) sx_lds[LAY][row] = pa_;                                       \
    u16x8 pk_;                                                                   \
    _Pragma("unroll")                                                            \
    for (int e_ = 0; e_ < 4; e_++) {                                             \
        pk_[e_]   = f2bf(pf[SET][0][e_]);                                        \
        pk_[e_+4] = f2bf(pf[SET][1][e_]);                                        \
    }                                                                            \
    *reinterpret_cast<u16x8*>(&A_lds[LAY][doff]) = pk_;                          \
} while (0)

#define LGKM_BARRIER() do {                                                      \
    asm volatile("s_waitcnt lgkmcnt(0)" ::: "memory");                           \
    __builtin_amdgcn_s_barrier();                                                \
} while (0)

    // ---- B double-buffer: preload step 0's 4 fragments ----
    bf16x8 Bc[4], Bn[4];
    #pragma unroll
    for (int c = 0; c < 4; c++)
        Bc[c] = *reinterpret_cast<const bf16x8*>(pB + (size_t)(c * 4 + kq) * 1024);

    // ---- prologue: 3 layers of loads in flight, convert layer 0 ----
    LOADS(0, 0);
    LOADS(1, 1);
    LOADS(2, 2);
    CONVERT_WRITE(0, 0);
    LGKM_BARRIER();

    // ---- main loop: 8 steps (step == layer), fully unrolled ----
    #pragma unroll
    for (int s = 0; s < 8; s++) {
        if (s + 3 < 8) LOADS((s + 3) % 3, s + 3);
        if (s + 1 < 8) CONVERT_WRITE((s + 1) % 3, s + 1);
        // prefetch next step's B fragments (in flight during MFMAs)
        if (s < 7) {
            const int k8n = (s + 1) * 16;
            #pragma unroll
            for (int c = 0; c < 4; c++)
                Bn[c] = *reinterpret_cast<const bf16x8*>(pB + (size_t)(k8n + c * 4 + kq) * 1024);
        }
        // MFMA on layer s's resident tile
        #pragma unroll
        for (int c = 0; c < 4; c++) {
            bf16x8 af[2];
            #pragma unroll
            for (int m = 0; m < 2; m++) {
                int r = m * 16 + colq;
                af[m] = *reinterpret_cast<const bf16x8*>(
                    &A_lds[s][r * 128 + (((c * 4 + kq) ^ colq) * 8)]);
            }
            acc[0] = __builtin_amdgcn_mfma_f32_16x16x32_bf16(af[0], Bc[c], acc[0], 0, 0, 0);
            acc[1] = __builtin_amdgcn_mfma_f32_16x16x32_bf16(af[1], Bc[c], acc[1], 0, 0, 0);
        }
        #pragma unroll
        for (int c = 0; c < 4; c++) Bc[c] = Bn[c];
        LGKM_BARRIER();
    }

    // ---- sjk: sum over this wave's 16 cols of prelu(jk + b_ref) * wa_ref ----
    // D layout: col = wave*16 + colq, node = m*16 + kq*4 + r
    #pragma unroll
    for (int m = 0; m < 2; m++) {
        float sr[4];
        #pragma unroll
        for (int r = 0; r < 4; r++) {
            float v = acc[m][r] + br;
            v = (v >= 0.f) ? v : alpha * v;
            float sv = v * wr;
            sv += __shfl_xor(sv, 1);
            sv += __shfl_xor(sv, 2);
            sv += __shfl_xor(sv, 4);
            sv += __shfl_xor(sv, 8);
            sr[r] = sv;
        }
        if (colq == 0) {
            #pragma unroll
            for (int r = 0; r < 4; r++)
                sjk_lds[m * 16 + kq * 4 + r][wave] = sr[r];
        }
    }
    __syncthreads();

    // ---- epilogue: softmax from LDS scores + weighted sum from LDS bf16 tiles ----
    // Thread handles (node = row, slot); xs NOT re-read.
    {
        const int node = row;
        const int boff = node * 128 + ((slot ^ (node & 15)) * 8);
        float sjk = 0.f;
        #pragma unroll
        for (int w8 = 0; w8 < 8; w8++) sjk += sjk_lds[node][w8];
        float sc[LL], mx = 0.f;
        #pragma unroll
        for (int l = 0; l < LL; l++) {
            float sv = sjk + sx_lds[l][node] + batt;
            sv = fmaxf(sv, 0.f);
            sc[l] = sv;
            mx = fmaxf(mx, sv);
        }
        float den = 0.f;
        #pragma unroll
        for (int l = 0; l < LL; l++) { sc[l] = __expf(sc[l] - mx); den += sc[l]; }
        float inv = 1.f / den;
        f32x4 o0 = (f32x4){0.f, 0.f, 0.f, 0.f};
        f32x4 o1 = (f32x4){0.f, 0.f, 0.f, 0.f};
        #pragma unroll
        for (int l = 0; l < LL; l++) {
            u16x8 v = *reinterpret_cast<const u16x8*>(&A_lds[l][boff]);
            float wl = sc[l] * inv;
            #pragma unroll
            for (int e = 0; e < 4; e++) {
                o0[e] += wl * bf2f(v[e]);
                o1[e] += wl * bf2f(v[e + 4]);
            }
        }
        float* op = out + (size_t)(n0 + node) * HH + slot * 8;
        __builtin_nontemporal_store(o0, reinterpret_cast<f32x4*>(op));
        __builtin_nontemporal_store(o1, reinterpret_cast<f32x4*>(op + 4));
    }
#undef LOADS
#undef CONVERT_WRITE
#undef LGKM_BARRIER
}

extern "C" void kernel_launch(void* const* d_in, const int* in_sizes, int n_in,
                              void* d_out, int out_size, void* d_ws, size_t ws_size,
                              hipStream_t stream) {
    const float* xs     = (const float*)d_in[0];
    const float* w_ref  = (const float*)d_in[1];
    const float* b_ref  = (const float*)d_in[2];
    const float* w_att  = (const float*)d_in[3];
    const float* b_att  = (const float*)d_in[4];
    const float* alpha  = (const float*)d_in[5];
    float* out = (float*)d_out;
    unsigned short* wp = (unsigned short*)d_ws;   // 256 KB packed bf16 weights

    pack_w_kernel<<<64, 256, 0, stream>>>(w_ref, wp);
    const int grid = NN / BM;                     // 3125, exact
    gamlp_main<<<grid, 512, 0, stream>>>(xs, wp, b_ref, w_att, b_att, alpha, out);
}